// Round 2
// baseline (1538.019 us; speedup 1.0000x reference)
//
#include <hip/hip_runtime.h>
#include <hip/hip_bf16.h>

#define H 224
#define W 224
#define C 256
#define F 256
#define OB 14

typedef __attribute__((ext_vector_type(8))) short short8;
typedef __attribute__((ext_vector_type(4))) float f32x4;

__device__ __forceinline__ unsigned short f2bf(float f) {
    union { float f; unsigned u; } v; v.f = f;
    unsigned r = v.u + 0x7fffu + ((v.u >> 16) & 1u);
    return (unsigned short)(r >> 16);
}

// ---------------------------------------------------------------------------
// Weight repack: kernel[ky][kx][c][f] fp32  ->  bf16 B-fragment-major layout
// wrep[((kt*16 + nt)*64 + lane)*8 + j] = bf16(w[kk][c32*32 + quad*8 + j][nt*16 + lq])
// ---------------------------------------------------------------------------
__global__ __launch_bounds__(256) void repack_kernel(const float* __restrict__ wsrc,
                                                     unsigned short* __restrict__ wrep) {
    int g = blockIdx.x * 256 + threadIdx.x;   // < 72*16*64 = 73728
    int lane = g & 63;
    int nt   = (g >> 6) & 15;
    int kt   = g >> 10;
    int kk   = kt >> 3, c32 = kt & 7;
    int quad = lane >> 4, lq = lane & 15;
    int cbase = c32 * 32 + quad * 8;
    int f = nt * 16 + lq;
    alignas(16) unsigned short tmp[8];
#pragma unroll
    for (int j = 0; j < 8; ++j) {
        tmp[j] = f2bf(wsrc[((size_t)(kk * 256 + cbase + j)) * 256 + f]);
    }
    *reinterpret_cast<uint4*>(wrep + (size_t)g * 8) = *reinterpret_cast<const uint4*>(tmp);
}

// ---------------------------------------------------------------------------
// Conv kernel: 1 workgroup (8 waves / 512 thr) per 14x14 output block.
// Computes its own active flag from the mask. Inactive -> zero-fill.
// Active -> bf16 MFMA implicit GEMM, M=196 (13x16), N=256 (wave: 2x16), K=2304.
// LDS patch layout XOR-swizzled: pixel p, 16B-granule g stored at g^(p&7).
// Bank for granule g', pixel p: 4*g' mod 32 -> swizzle spreads the quad's 16
// pixels across 8 bank-groups (2-way = free) instead of 16-way on one bank.
// ---------------------------------------------------------------------------
__global__ __launch_bounds__(512, 4) void conv_kernel(const float* __restrict__ in,
                                                      const float* __restrict__ mask,
                                                      const unsigned short* __restrict__ wrep,
                                                      const float* __restrict__ bias,
                                                      float* __restrict__ out) {
    __shared__ __align__(16) unsigned short patch[256 * 128];  // 64 KB

    const int b = blockIdx.x;
    const int n = b >> 8, by = (b >> 4) & 15, bx = b & 15;
    const int tid = threadIdx.x;
    const int gy0 = by * OB - 1, gx0 = bx * OB - 1;
    float* outB = out + (size_t)n * H * W * F;

    // ---- active flag: mean of 16x16 padded mask patch > 0.5 ----
    float* red = reinterpret_cast<float*>(patch);
    if (tid < 256) {
        int r = tid >> 4, s = tid & 15;
        int gy = gy0 + r, gx = gx0 + s;
        float v = 0.f;
        if ((unsigned)gy < (unsigned)H && (unsigned)gx < (unsigned)W)
            v = mask[((size_t)n * H + gy) * W + gx];
        red[tid] = v;
    }
    __syncthreads();
    if (tid < 64) {
        float v = red[tid] + red[tid + 64] + red[tid + 128] + red[tid + 192];
#pragma unroll
        for (int off = 32; off; off >>= 1) v += __shfl_down(v, off);
        if (tid == 0) red[0] = v;
    }
    __syncthreads();
    const bool active = red[0] > (0.5f * 256.0f);

    if (!active) {
        for (int idx = tid; idx < 196 * 64; idx += 512) {
            int pix = idx >> 6, fv = idx & 63;
            int oy = pix / 14, ox = pix - oy * 14;
            size_t o = ((size_t)((by * OB + oy) * W + bx * OB + ox)) * F + fv * 4;
            *reinterpret_cast<float4*>(outB + o) = make_float4(0.f, 0.f, 0.f, 0.f);
        }
        return;
    }

    const int wave = tid >> 6, lane = tid & 63;
    const int quad = lane >> 4, lq = lane & 15;
    const int f0 = wave * 32 + lq, f1 = f0 + 16;
    const int nt0 = wave * 2;

    // Per-M-tile pixel index (within 16x16 patch) of this lane's output pixel
    int pixv[13];
#pragma unroll
    for (int mt = 0; mt < 13; ++mt) {
        int p = mt * 16 + lq;
        if (p > 195) p = 195;               // clamp tail tile (stores guarded later)
        int oy = p / 14, ox = p - oy * 14;
        pixv[mt] = oy * 16 + ox;
    }

    f32x4 acc[13][2];
#pragma unroll
    for (int mt = 0; mt < 13; ++mt) {
        acc[mt][0] = (f32x4)(0.f);
        acc[mt][1] = (f32x4)(0.f);
    }

    const float* inB = in + (size_t)n * H * W * C;

    for (int cc = 0; cc < 2; ++cc) {
        __syncthreads();  // protect patch from previous readers (incl. red[])
        // stage 16x16 x 128ch chunk: fp32 -> bf16 -> swizzled LDS
        for (int it = 0; it < 16; ++it) {
            int idx = tid + it * 512;       // 8192 uint2 units
            int pix = idx >> 5, chv = idx & 31;
            int r = pix >> 4, s = pix & 15;
            int gy = gy0 + r, gx = gx0 + s;
            float4 v = make_float4(0.f, 0.f, 0.f, 0.f);
            if ((unsigned)gy < (unsigned)H && (unsigned)gx < (unsigned)W)
                v = *reinterpret_cast<const float4*>(inB + ((size_t)(gy * W + gx)) * C + cc * 128 + chv * 4);
            uint2 bb;
            bb.x = (unsigned)f2bf(v.x) | ((unsigned)f2bf(v.y) << 16);
            bb.y = (unsigned)f2bf(v.z) | ((unsigned)f2bf(v.w) << 16);
            int g = chv >> 1, hh = chv & 1;
            int soff = (pix << 7) + (((g ^ (pix & 7)) << 3)) + (hh << 2);
            *reinterpret_cast<uint2*>(&patch[soff]) = bb;
        }
        __syncthreads();

#pragma unroll
        for (int ky = 0; ky < 3; ++ky) {
#pragma unroll
            for (int kx = 0; kx < 3; ++kx) {
                const int kk = ky * 3 + kx;
                const int kadd = ky * 16 + kx;
#pragma unroll
                for (int c32l = 0; c32l < 4; ++c32l) {
                    const int ktg = kk * 8 + cc * 4 + c32l;
                    const size_t wo = ((size_t)(ktg * 16 + nt0) * 64 + lane) * 8;
                    short8 b0 = *reinterpret_cast<const short8*>(wrep + wo);
                    short8 b1 = *reinterpret_cast<const short8*>(wrep + wo + 64 * 8);
                    const int gq = (c32l << 2) + quad;
#pragma unroll
                    for (int mt = 0; mt < 13; ++mt) {
                        const int s = pixv[mt] + kadd;
                        const int aoff = (s << 7) + ((gq ^ (s & 7)) << 3);
                        short8 a = *reinterpret_cast<const short8*>(&patch[aoff]);
                        acc[mt][0] = __builtin_amdgcn_mfma_f32_16x16x32_bf16(a, b0, acc[mt][0], 0, 0, 0);
                        acc[mt][1] = __builtin_amdgcn_mfma_f32_16x16x32_bf16(a, b1, acc[mt][1], 0, 0, 0);
                    }
                }
            }
        }
    }

    // Epilogue: bias + relu + store. D layout: col = lane&15, row = quad*4 + reg.
    const float bv0 = bias[f0], bv1 = bias[f1];
#pragma unroll
    for (int mt = 0; mt < 13; ++mt) {
#pragma unroll
        for (int j = 0; j < 4; ++j) {
            int p = mt * 16 + quad * 4 + j;
            if (p < 196) {
                int oy = p / 14, ox = p - oy * 14;
                size_t o = ((size_t)((by * OB + oy) * W + bx * OB + ox)) * F;
                float v0 = acc[mt][0][j] + bv0;
                float v1 = acc[mt][1][j] + bv1;
                outB[o + f0] = v0 > 0.f ? v0 : 0.f;
                outB[o + f1] = v1 > 0.f ? v1 : 0.f;
            }
        }
    }
}

extern "C" void kernel_launch(void* const* d_in, const int* in_sizes, int n_in,
                              void* d_out, int out_size, void* d_ws, size_t ws_size,
                              hipStream_t stream) {
    const float* inputs = (const float*)d_in[0];
    const float* mask   = (const float*)d_in[1];
    const float* wsrc   = (const float*)d_in[2];
    const float* bias   = (const float*)d_in[3];
    float* outp = (float*)d_out;

    unsigned short* wrep = (unsigned short*)d_ws;   // 72*16*64*8 bf16 = 1.18 MB

    hipLaunchKernelGGL(repack_kernel, dim3(288), dim3(256), 0, stream, wsrc, wrep);
    hipLaunchKernelGGL(conv_kernel, dim3(1024), dim3(512), 0, stream, inputs, mask, wrep, bias, outp);
}

// Round 3
// 676.847 us; speedup vs baseline: 2.2723x; 2.2723x over previous
//
#include <hip/hip_runtime.h>
#include <hip/hip_bf16.h>

#define H 224
#define W 224
#define C 256
#define F 256
#define OB 14

typedef __attribute__((ext_vector_type(8))) short short8;
typedef __attribute__((ext_vector_type(4))) float f32x4;

__device__ __forceinline__ unsigned short f2bf(float f) {
    union { float f; unsigned u; } v; v.f = f;
    unsigned r = v.u + 0x7fffu + ((v.u >> 16) & 1u);
    return (unsigned short)(r >> 16);
}

// ---------------------------------------------------------------------------
// Weight repack: kernel[ky][kx][c][f] fp32  ->  bf16 B-fragment-major layout
// wrep[((kt*16 + nt)*64 + lane)*8 + j] = bf16(w[kk][c32*32 + quad*8 + j][nt*16 + lq])
// ---------------------------------------------------------------------------
__global__ __launch_bounds__(256) void repack_kernel(const float* __restrict__ wsrc,
                                                     unsigned short* __restrict__ wrep) {
    int g = blockIdx.x * 256 + threadIdx.x;   // < 72*16*64 = 73728
    int lane = g & 63;
    int nt   = (g >> 6) & 15;
    int kt   = g >> 10;
    int kk   = kt >> 3, c32 = kt & 7;
    int quad = lane >> 4, lq = lane & 15;
    int cbase = c32 * 32 + quad * 8;
    int f = nt * 16 + lq;
    alignas(16) unsigned short tmp[8];
#pragma unroll
    for (int j = 0; j < 8; ++j) {
        tmp[j] = f2bf(wsrc[((size_t)(kk * 256 + cbase + j)) * 256 + f]);
    }
    *reinterpret_cast<uint4*>(wrep + (size_t)g * 8) = *reinterpret_cast<const uint4*>(tmp);
}

__global__ void init_kernel(int* __restrict__ cnt) {
    cnt[0] = 0;
    cnt[1] = 0;
}

// ---------------------------------------------------------------------------
// Flags + compaction: active block ids packed to front of list, inactive to back.
// ---------------------------------------------------------------------------
__global__ __launch_bounds__(256) void flags_kernel(const float* __restrict__ mask,
                                                    int* __restrict__ list,
                                                    int* __restrict__ cnt) {
    int b = blockIdx.x;                 // (n, by, bx)
    int n = b >> 8, by = (b >> 4) & 15, bx = b & 15;
    int t = threadIdx.x;
    int r = t >> 4, s = t & 15;
    int gy = by * OB - 1 + r, gx = bx * OB - 1 + s;
    float v = 0.f;
    if ((unsigned)gy < (unsigned)H && (unsigned)gx < (unsigned)W)
        v = mask[((size_t)n * H + gy) * W + gx];
    __shared__ float red[256];
    red[t] = v;
    __syncthreads();
    if (t < 64) {
        float x = red[t] + red[t + 64] + red[t + 128] + red[t + 192];
#pragma unroll
        for (int off = 32; off; off >>= 1) x += __shfl_down(x, off);
        if (t == 0) {
            if (x > 0.5f * 256.0f) {
                int p = atomicAdd(&cnt[0], 1);
                list[p] = b;
            } else {
                int p = atomicAdd(&cnt[1], 1);
                list[1023 - p] = b;
            }
        }
    }
}

// ---------------------------------------------------------------------------
// Conv kernel: 1 workgroup (8 waves) per 14x14x256 output block, via work list.
// bid < n_active -> MFMA implicit GEMM; else zero-fill.
// Wave tiling 2Mx4N: wave owns 7 output rows x 64 output channels.
//   M-tile = one output row (14 valid cols of 16), so A-frag lanes read 16
//   CONSECUTIVE patch pixels; 4-bit XOR swizzle (granule ^ pix&15) makes each
//   quad's 16 lanes hit 16 distinct 16B granules -> conflict-free ds_read_b128.
// Each A-read feeds 4 MFMAs (4 N-tiles) -> 4032 ds_read_b128 per block.
// acc[7][4] f32x4 = 112 regs; launch_bounds(512,2) -> 256 unified regs/wave,
// no spill (R2's (512,4) forced 128 -> accumulator spill -> 900MB scratch).
// ---------------------------------------------------------------------------
__global__ __launch_bounds__(512, 2) void conv_kernel(const float* __restrict__ in,
                                                      const unsigned short* __restrict__ wrep,
                                                      const float* __restrict__ bias,
                                                      const int* __restrict__ list,
                                                      const int* __restrict__ cnt,
                                                      float* __restrict__ out) {
    __shared__ __align__(16) unsigned short patch[256 * 128];  // 64 KB

    const int bid = blockIdx.x;
    const int n_active = cnt[0];
    const int b = list[bid];
    const int n = b >> 8, by = (b >> 4) & 15, bx = b & 15;
    const int tid = threadIdx.x;
    const int gy0 = by * OB - 1, gx0 = bx * OB - 1;
    float* outB = out + (size_t)n * H * W * F;

    if (bid >= n_active) {
        for (int idx = tid; idx < 196 * 64; idx += 512) {
            int pix = idx >> 6, fv = idx & 63;
            int oy = pix / 14, ox = pix - oy * 14;
            size_t o = ((size_t)((by * OB + oy) * W + bx * OB + ox)) * F + fv * 4;
            *reinterpret_cast<float4*>(outB + o) = make_float4(0.f, 0.f, 0.f, 0.f);
        }
        return;
    }

    const int wave = tid >> 6, lane = tid & 63;
    const int quad = lane >> 4, lq = lane & 15;
    const int wm = wave >> 2;          // 0..1 : rows wm*7 .. wm*7+6
    const int wn = wave & 3;           // 0..3 : f-tiles wn*4 .. wn*4+3

    f32x4 acc[7][4];
#pragma unroll
    for (int r = 0; r < 7; ++r)
#pragma unroll
        for (int i = 0; i < 4; ++i) acc[r][i] = (f32x4)(0.f);

    const float* inB = in + (size_t)n * H * W * C;
    // clamp garbage M lanes (lq=14,15) so patch reads stay in-bounds
    const int scol_base = (lq > 13) ? 13 : lq;

    for (int cc = 0; cc < 2; ++cc) {
        __syncthreads();
        // stage 16x16 x 128ch chunk: fp32 -> bf16 -> 4-bit-XOR-swizzled LDS
        for (int it = 0; it < 16; ++it) {
            int idx = tid + it * 512;       // 8192 uint2 units
            int pix = idx >> 5, chv = idx & 31;
            int r = pix >> 4, s = pix & 15;
            int gy = gy0 + r, gx = gx0 + s;
            float4 v = make_float4(0.f, 0.f, 0.f, 0.f);
            if ((unsigned)gy < (unsigned)H && (unsigned)gx < (unsigned)W)
                v = *reinterpret_cast<const float4*>(inB + ((size_t)(gy * W + gx)) * C + cc * 128 + chv * 4);
            uint2 bb;
            bb.x = (unsigned)f2bf(v.x) | ((unsigned)f2bf(v.y) << 16);
            bb.y = (unsigned)f2bf(v.z) | ((unsigned)f2bf(v.w) << 16);
            int g = chv >> 1, hh = chv & 1;
            int soff = (pix << 7) + ((g ^ (pix & 15)) << 3) + (hh << 2);
            *reinterpret_cast<uint2*>(&patch[soff]) = bb;
        }
        __syncthreads();

#pragma unroll
        for (int ky = 0; ky < 3; ++ky) {
#pragma unroll
            for (int kx = 0; kx < 3; ++kx) {
                const int kk = ky * 3 + kx;
                const int scol = scol_base + kx;      // <= 15
#pragma unroll
                for (int c32l = 0; c32l < 4; ++c32l) {
                    const int ktg = kk * 8 + cc * 4 + c32l;
                    short8 bfr[4];
#pragma unroll
                    for (int i = 0; i < 4; ++i) {
                        const int nt = wn * 4 + i;
                        bfr[i] = *reinterpret_cast<const short8*>(
                            wrep + ((size_t)(ktg * 16 + nt) * 64 + lane) * 8);
                    }
                    const int gq = (c32l << 2) + quad;
#pragma unroll
                    for (int r = 0; r < 7; ++r) {
                        const int srow = wm * 7 + r + ky;          // <= 15
                        const int s = (srow << 4) + scol;
                        const int aoff = (s << 7) + ((gq ^ (s & 15)) << 3);
                        short8 a = *reinterpret_cast<const short8*>(&patch[aoff]);
#pragma unroll
                        for (int i = 0; i < 4; ++i)
                            acc[r][i] = __builtin_amdgcn_mfma_f32_16x16x32_bf16(a, bfr[i], acc[r][i], 0, 0, 0);
                    }
                }
            }
        }
    }

    // Epilogue. D layout: M-index (output col) = quad*4 + reg, N-index = lane&15.
    float bv[4];
#pragma unroll
    for (int i = 0; i < 4; ++i) bv[i] = bias[wn * 64 + i * 16 + lq];
#pragma unroll
    for (int r = 0; r < 7; ++r) {
        const int oy = wm * 7 + r;
#pragma unroll
        for (int j = 0; j < 4; ++j) {
            const int ox = quad * 4 + j;
            if (ox < 14) {
                size_t o = ((size_t)((by * OB + oy) * W + bx * OB + ox)) * F + wn * 64 + lq;
#pragma unroll
                for (int i = 0; i < 4; ++i) {
                    float v = acc[r][i][j] + bv[i];
                    outB[o + i * 16] = v > 0.f ? v : 0.f;
                }
            }
        }
    }
}

extern "C" void kernel_launch(void* const* d_in, const int* in_sizes, int n_in,
                              void* d_out, int out_size, void* d_ws, size_t ws_size,
                              hipStream_t stream) {
    const float* inputs = (const float*)d_in[0];
    const float* mask   = (const float*)d_in[1];
    const float* wsrc   = (const float*)d_in[2];
    const float* bias   = (const float*)d_in[3];
    float* outp = (float*)d_out;

    unsigned short* wrep = (unsigned short*)d_ws;              // 1,179,648 B
    int* list = (int*)((char*)d_ws + 1179648);                 // 1024 ints
    int* cnt  = (int*)((char*)d_ws + 1179648 + 4096);          // 2 ints

    hipLaunchKernelGGL(init_kernel, dim3(1), dim3(1), 0, stream, cnt);
    hipLaunchKernelGGL(repack_kernel, dim3(288), dim3(256), 0, stream, wsrc, wrep);
    hipLaunchKernelGGL(flags_kernel, dim3(1024), dim3(256), 0, stream, mask, list, cnt);
    hipLaunchKernelGGL(conv_kernel, dim3(1024), dim3(512), 0, stream,
                       inputs, wrep, bias, list, cnt, outp);
}

// Round 4
// 434.944 us; speedup vs baseline: 3.5361x; 1.5562x over previous
//
#include <hip/hip_runtime.h>
#include <hip/hip_bf16.h>

#define H 224
#define W 224
#define C 256
#define F 256
#define OB 14

typedef __attribute__((ext_vector_type(8))) short short8;
typedef __attribute__((ext_vector_type(4))) float f32x4;

__device__ __forceinline__ unsigned short f2bf(float f) {
    union { float f; unsigned u; } v; v.f = f;
    unsigned r = v.u + 0x7fffu + ((v.u >> 16) & 1u);
    return (unsigned short)(r >> 16);
}

// ---------------------------------------------------------------------------
// Weight repack: kernel[ky][kx][c][f] fp32  ->  bf16 B-fragment-major layout
// wrep[((kt*16 + nt)*64 + lane)*8 + j] = bf16(w[kk][c32*32 + quad*8 + j][nt*16 + lq])
// ---------------------------------------------------------------------------
__global__ __launch_bounds__(256) void repack_kernel(const float* __restrict__ wsrc,
                                                     unsigned short* __restrict__ wrep) {
    int g = blockIdx.x * 256 + threadIdx.x;   // < 72*16*64 = 73728
    int lane = g & 63;
    int nt   = (g >> 6) & 15;
    int kt   = g >> 10;
    int kk   = kt >> 3, c32 = kt & 7;
    int quad = lane >> 4, lq = lane & 15;
    int cbase = c32 * 32 + quad * 8;
    int f = nt * 16 + lq;
    alignas(16) unsigned short tmp[8];
#pragma unroll
    for (int j = 0; j < 8; ++j) {
        tmp[j] = f2bf(wsrc[((size_t)(kk * 256 + cbase + j)) * 256 + f]);
    }
    *reinterpret_cast<uint4*>(wrep + (size_t)g * 8) = *reinterpret_cast<const uint4*>(tmp);
}

__global__ void init_kernel(int* __restrict__ cnt) {
    cnt[0] = 0;
    cnt[1] = 0;
}

// ---------------------------------------------------------------------------
// Flags + compaction: active block ids packed to front of list, inactive to back.
// ---------------------------------------------------------------------------
__global__ __launch_bounds__(256) void flags_kernel(const float* __restrict__ mask,
                                                    int* __restrict__ list,
                                                    int* __restrict__ cnt) {
    int b = blockIdx.x;                 // (n, by, bx)
    int n = b >> 8, by = (b >> 4) & 15, bx = b & 15;
    int t = threadIdx.x;
    int r = t >> 4, s = t & 15;
    int gy = by * OB - 1 + r, gx = bx * OB - 1 + s;
    float v = 0.f;
    if ((unsigned)gy < (unsigned)H && (unsigned)gx < (unsigned)W)
        v = mask[((size_t)n * H + gy) * W + gx];
    __shared__ float red[256];
    red[t] = v;
    __syncthreads();
    if (t < 64) {
        float x = red[t] + red[t + 64] + red[t + 128] + red[t + 192];
#pragma unroll
        for (int off = 32; off; off >>= 1) x += __shfl_down(x, off);
        if (t == 0) {
            if (x > 0.5f * 256.0f) {
                int p = atomicAdd(&cnt[0], 1);
                list[p] = b;
            } else {
                int p = atomicAdd(&cnt[1], 1);
                list[1023 - p] = b;
            }
        }
    }
}

// ---------------------------------------------------------------------------
// Conv: 1 workgroup (8 waves) per 14x14x256 block via compacted work list.
// Wave tiling 2Mx4N: 7 output rows x 64 channels, acc[7][4] f32x4 = 112 regs.
// REGISTER-PRESSURE DISCIPLINE (R2/R3 both spilled to scratch):
//   - ky/kx rolled (#pragma unroll 1): no cross-tap hoisting
//   - c32l unrolled x2 only: hoisted live set ~ 8 B-frags + 14 A-frags
//   - staging loop unrolled x4 only
// LDS: 4-bit XOR swizzle (16B granule ^ pix&15) -> conflict-free ds_read_b128.
// ---------------------------------------------------------------------------
__global__ __launch_bounds__(512, 2) void conv_kernel(const float* __restrict__ in,
                                                      const unsigned short* __restrict__ wrep,
                                                      const float* __restrict__ bias,
                                                      const int* __restrict__ list,
                                                      const int* __restrict__ cnt,
                                                      float* __restrict__ out) {
    __shared__ __align__(16) unsigned short patch[256 * 128];  // 64 KB

    const int bid = blockIdx.x;
    const int n_active = cnt[0];
    const int b = list[bid];
    const int n = b >> 8, by = (b >> 4) & 15, bx = b & 15;
    const int tid = threadIdx.x;
    const int gy0 = by * OB - 1, gx0 = bx * OB - 1;
    float* outB = out + (size_t)n * H * W * F;

    if (bid >= n_active) {
#pragma unroll 4
        for (int idx = tid; idx < 196 * 64; idx += 512) {
            int pix = idx >> 6, fv = idx & 63;
            int oy = pix / 14, ox = pix - oy * 14;
            size_t o = ((size_t)((by * OB + oy) * W + bx * OB + ox)) * F + fv * 4;
            *reinterpret_cast<float4*>(outB + o) = make_float4(0.f, 0.f, 0.f, 0.f);
        }
        return;
    }

    const int wave = tid >> 6, lane = tid & 63;
    const int quad = lane >> 4, lq = lane & 15;
    const int wm = wave >> 2;          // 0..1 : rows wm*7 .. wm*7+6
    const int wn = wave & 3;           // 0..3 : f-tiles wn*4 .. wn*4+3

    f32x4 acc[7][4];
#pragma unroll
    for (int r = 0; r < 7; ++r)
#pragma unroll
        for (int i = 0; i < 4; ++i) acc[r][i] = (f32x4)(0.f);

    const float* inB = in + (size_t)n * H * W * C;
    const int scol_base = (lq > 13) ? 13 : lq;   // clamp garbage M lanes
    const unsigned short* wrep_w = wrep + ((size_t)(wn * 4) * 64 + lane) * 8;

    for (int cc = 0; cc < 2; ++cc) {
        __syncthreads();
        // stage 16x16 x 128ch chunk: fp32 -> bf16 -> 4-bit-XOR-swizzled LDS
#pragma unroll 4
        for (int it = 0; it < 16; ++it) {
            int idx = tid + it * 512;       // 8192 uint2 units
            int pix = idx >> 5, chv = idx & 31;
            int r = pix >> 4, s = pix & 15;
            int gy = gy0 + r, gx = gx0 + s;
            float4 v = make_float4(0.f, 0.f, 0.f, 0.f);
            if ((unsigned)gy < (unsigned)H && (unsigned)gx < (unsigned)W)
                v = *reinterpret_cast<const float4*>(inB + ((size_t)(gy * W + gx)) * C + cc * 128 + chv * 4);
            uint2 bb;
            bb.x = (unsigned)f2bf(v.x) | ((unsigned)f2bf(v.y) << 16);
            bb.y = (unsigned)f2bf(v.z) | ((unsigned)f2bf(v.w) << 16);
            int g = chv >> 1, hh = chv & 1;
            int soff = (pix << 7) + ((g ^ (pix & 15)) << 3) + (hh << 2);
            *reinterpret_cast<uint2*>(&patch[soff]) = bb;
        }
        __syncthreads();

#pragma unroll 1
        for (int ky = 0; ky < 3; ++ky) {
#pragma unroll 1
            for (int kx = 0; kx < 3; ++kx) {
                const int kk = ky * 3 + kx;
                const int scol = scol_base + kx;                       // <= 15
                const unsigned short* bp = wrep_w + (size_t)(kk * 8 + cc * 4) * 8192;
                const int sb = (((wm * 7 + ky) << 4) + scol) << 7;     // r=0 elem offset
#pragma unroll 2
                for (int c32l = 0; c32l < 4; ++c32l) {
                    const unsigned short* bpc = bp + c32l * 8192;
                    short8 b0 = *reinterpret_cast<const short8*>(bpc);
                    short8 b1 = *reinterpret_cast<const short8*>(bpc + 512);
                    short8 b2 = *reinterpret_cast<const short8*>(bpc + 1024);
                    short8 b3 = *reinterpret_cast<const short8*>(bpc + 1536);
                    const int gq = (c32l << 2) + quad;
                    const unsigned short* ap = &patch[sb + ((gq ^ scol) << 3)];
#pragma unroll
                    for (int r = 0; r < 7; ++r) {
                        short8 a = *reinterpret_cast<const short8*>(ap + r * 2048);
                        acc[r][0] = __builtin_amdgcn_mfma_f32_16x16x32_bf16(a, b0, acc[r][0], 0, 0, 0);
                        acc[r][1] = __builtin_amdgcn_mfma_f32_16x16x32_bf16(a, b1, acc[r][1], 0, 0, 0);
                        acc[r][2] = __builtin_amdgcn_mfma_f32_16x16x32_bf16(a, b2, acc[r][2], 0, 0, 0);
                        acc[r][3] = __builtin_amdgcn_mfma_f32_16x16x32_bf16(a, b3, acc[r][3], 0, 0, 0);
                    }
                }
            }
        }
    }

    // Epilogue. D layout: M-index (output col) = quad*4 + reg, N-index = lane&15.
    float bv[4];
#pragma unroll
    for (int i = 0; i < 4; ++i) bv[i] = bias[wn * 64 + i * 16 + lq];
#pragma unroll
    for (int r = 0; r < 7; ++r) {
        const int oy = wm * 7 + r;
#pragma unroll
        for (int j = 0; j < 4; ++j) {
            const int ox = quad * 4 + j;
            if (ox < 14) {
                size_t o = ((size_t)((by * OB + oy) * W + bx * OB + ox)) * F + wn * 64 + lq;
#pragma unroll
                for (int i = 0; i < 4; ++i) {
                    float v = acc[r][i][j] + bv[i];
                    outB[o + i * 16] = v > 0.f ? v : 0.f;
                }
            }
        }
    }
}

extern "C" void kernel_launch(void* const* d_in, const int* in_sizes, int n_in,
                              void* d_out, int out_size, void* d_ws, size_t ws_size,
                              hipStream_t stream) {
    const float* inputs = (const float*)d_in[0];
    const float* mask   = (const float*)d_in[1];
    const float* wsrc   = (const float*)d_in[2];
    const float* bias   = (const float*)d_in[3];
    float* outp = (float*)d_out;

    unsigned short* wrep = (unsigned short*)d_ws;              // 1,179,648 B
    int* list = (int*)((char*)d_ws + 1179648);                 // 1024 ints
    int* cnt  = (int*)((char*)d_ws + 1179648 + 4096);          // 2 ints

    hipLaunchKernelGGL(init_kernel, dim3(1), dim3(1), 0, stream, cnt);
    hipLaunchKernelGGL(repack_kernel, dim3(288), dim3(256), 0, stream, wsrc, wrep);
    hipLaunchKernelGGL(flags_kernel, dim3(1024), dim3(256), 0, stream, mask, list, cnt);
    hipLaunchKernelGGL(conv_kernel, dim3(1024), dim3(512), 0, stream,
                       inputs, wrep, bias, list, cnt, outp);
}